// Round 1
// baseline (1083.096 us; speedup 1.0000x reference)
//
#include <hip/hip_runtime.h>

constexpr int NN = 50000;   // nodes
constexpr int NE = 800000;  // edges
constexpr int KV = 300;     // vocab / in_dim
constexpr int DE = 256;     // embed
constexpr int DF = 128;     // fc dim
constexpr int NC = 4;       // classes

// ------------------------------------------------------------------ CSR build
__global__ __launch_bounds__(256) void k_degree(const int* __restrict__ dst,
                                                int* __restrict__ deg) {
    int e = blockIdx.x * 256 + threadIdx.x;
    if (e < NE) atomicAdd(&deg[dst[e]], 1);
}

__global__ __launch_bounds__(256) void k_scan1(const int* __restrict__ deg,
                                               int* __restrict__ partial) {
    __shared__ int sd[256];
    int t = threadIdx.x;
    int n = blockIdx.x * 256 + t;
    sd[t] = (n < NN) ? deg[n] : 0;
    __syncthreads();
    for (int off = 128; off > 0; off >>= 1) {
        if (t < off) sd[t] += sd[t + off];
        __syncthreads();
    }
    if (t == 0) partial[blockIdx.x] = sd[0];
}

__global__ __launch_bounds__(256) void k_scan2(const int* __restrict__ partial,
                                               int* __restrict__ poff, int nb) {
    __shared__ int sd[256];
    int t = threadIdx.x;
    int v = (t < nb) ? partial[t] : 0;
    sd[t] = v;
    __syncthreads();
    for (int off = 1; off < 256; off <<= 1) {
        int x = (t >= off) ? sd[t - off] : 0;
        __syncthreads();
        sd[t] += x;
        __syncthreads();
    }
    poff[t] = sd[t] - v;  // exclusive prefix of block sums
}

__global__ __launch_bounds__(256) void k_scan3(const int* __restrict__ deg,
                                               const int* __restrict__ poff,
                                               int* __restrict__ rowptr) {
    __shared__ int sd[256];
    int t = threadIdx.x;
    int n = blockIdx.x * 256 + t;
    int v = (n < NN) ? deg[n] : 0;
    sd[t] = v;
    __syncthreads();
    for (int off = 1; off < 256; off <<= 1) {
        int x = (t >= off) ? sd[t - off] : 0;
        __syncthreads();
        sd[t] += x;
        __syncthreads();
    }
    if (n < NN) rowptr[n] = poff[blockIdx.x] + sd[t] - v;
    if (blockIdx.x == 0 && t == 0) rowptr[NN] = NE;
}

__global__ __launch_bounds__(256) void k_scatter(const int* __restrict__ src,
                                                 const int* __restrict__ dst,
                                                 const int* __restrict__ rowptr,
                                                 int* __restrict__ cnt2,
                                                 int* __restrict__ col) {
    int e = blockIdx.x * 256 + threadIdx.x;
    if (e < NE) {
        int d = dst[e];
        int p = rowptr[d] + atomicAdd(&cnt2[d], 1);
        col[p] = src[e];
    }
}

// ------------------------------------------------------------------ fp32 GEMM
// C[M,Nc] = A[M,K] @ W[Nc,K]^T ; 64x64 tile, BK=16, 4x4 per thread.
__global__ __launch_bounds__(256) void k_gemm(const float* __restrict__ A,
                                              const float* __restrict__ W,
                                              float* __restrict__ C,
                                              int M, int K, int Nc) {
    __shared__ float As[16][64];
    __shared__ float Bs[16][64];
    int bm = blockIdx.y * 64;
    int bn = blockIdx.x * 64;
    int t  = threadIdx.x;
    int tx = t & 15;        // col group
    int ty = t >> 4;        // row group
    int lr = t >> 2;        // 0..63 tile row for loads
    int lc = (t & 3) * 4;   // k offset 0,4,8,12

    float acc[4][4];
#pragma unroll
    for (int i = 0; i < 4; ++i)
#pragma unroll
        for (int j = 0; j < 4; ++j) acc[i][j] = 0.f;

    for (int k0 = 0; k0 < K; k0 += 16) {
        // ---- A tile
        {
            int gm = bm + lr;
            float4 v = {0.f, 0.f, 0.f, 0.f};
            if (gm < M) {
                const float* s = A + (size_t)gm * K + k0 + lc;
                if (k0 + lc + 3 < K) {
                    v = *(const float4*)s;
                } else {
                    float tmp[4] = {0.f, 0.f, 0.f, 0.f};
#pragma unroll
                    for (int i = 0; i < 4; ++i)
                        if (k0 + lc + i < K) tmp[i] = s[i];
                    v = make_float4(tmp[0], tmp[1], tmp[2], tmp[3]);
                }
            }
            As[lc + 0][lr] = v.x; As[lc + 1][lr] = v.y;
            As[lc + 2][lr] = v.z; As[lc + 3][lr] = v.w;
        }
        // ---- B tile (weight rows = output cols)
        {
            int gn = bn + lr;
            float4 v = {0.f, 0.f, 0.f, 0.f};
            if (gn < Nc) {
                const float* s = W + (size_t)gn * K + k0 + lc;
                if (k0 + lc + 3 < K) {
                    v = *(const float4*)s;
                } else {
                    float tmp[4] = {0.f, 0.f, 0.f, 0.f};
#pragma unroll
                    for (int i = 0; i < 4; ++i)
                        if (k0 + lc + i < K) tmp[i] = s[i];
                    v = make_float4(tmp[0], tmp[1], tmp[2], tmp[3]);
                }
            }
            Bs[lc + 0][lr] = v.x; Bs[lc + 1][lr] = v.y;
            Bs[lc + 2][lr] = v.z; Bs[lc + 3][lr] = v.w;
        }
        __syncthreads();
#pragma unroll
        for (int kk = 0; kk < 16; ++kk) {
            float4 a = *(const float4*)&As[kk][ty * 4];
            float4 b = *(const float4*)&Bs[kk][tx * 4];
            acc[0][0] += a.x * b.x; acc[0][1] += a.x * b.y;
            acc[0][2] += a.x * b.z; acc[0][3] += a.x * b.w;
            acc[1][0] += a.y * b.x; acc[1][1] += a.y * b.y;
            acc[1][2] += a.y * b.z; acc[1][3] += a.y * b.w;
            acc[2][0] += a.z * b.x; acc[2][1] += a.z * b.y;
            acc[2][2] += a.z * b.z; acc[2][3] += a.z * b.w;
            acc[3][0] += a.w * b.x; acc[3][1] += a.w * b.y;
            acc[3][2] += a.w * b.z; acc[3][3] += a.w * b.w;
        }
        __syncthreads();
    }
#pragma unroll
    for (int i = 0; i < 4; ++i) {
        int gm = bm + ty * 4 + i;
        if (gm < M) {
            float4 v = make_float4(acc[i][0], acc[i][1], acc[i][2], acc[i][3]);
            *(float4*)(C + (size_t)gm * Nc + bn + tx * 4) = v;
        }
    }
}

// --------------------------------------------------- aggregate + norm (+relu)
// one wave per node; lane l owns dims 4l..4l+3
__global__ __launch_bounds__(256) void k_aggnorm(const float* __restrict__ yl,
                                                 const float* __restrict__ yr,
                                                 const float* __restrict__ bias,
                                                 const int* __restrict__ rowptr,
                                                 const int* __restrict__ col,
                                                 float* __restrict__ outp,
                                                 int relu) {
    int wave = threadIdx.x >> 6;
    int lane = threadIdx.x & 63;
    int n = blockIdx.x * 4 + wave;
    if (n >= NN) return;
    int beg = rowptr[n], end = rowptr[n + 1];
    float4 acc = {0.f, 0.f, 0.f, 0.f};
    for (int e = beg; e < end; ++e) {
        int s = col[e];
        float4 v = *(const float4*)(yl + (size_t)s * DE + lane * 4);
        acc.x += v.x; acc.y += v.y; acc.z += v.z; acc.w += v.w;
    }
    int d = end - beg;
    float inv = 1.0f / (float)(d > 1 ? d : 1);
    float4 b = *(const float4*)(bias + lane * 4);
    float4 r = *(const float4*)(yr + (size_t)n * DE + lane * 4);
    float4 h;
    h.x = acc.x * inv + b.x + r.x;
    h.y = acc.y * inv + b.y + r.y;
    h.z = acc.z * inv + b.z + r.z;
    h.w = acc.w * inv + b.w + r.w;
    float ss = h.x * h.x + h.y * h.y + h.z * h.z + h.w * h.w;
#pragma unroll
    for (int off = 32; off > 0; off >>= 1) ss += __shfl_xor(ss, off, 64);
    float scale = 1.0f / fmaxf(sqrtf(ss), 1e-12f);
    h.x *= scale; h.y *= scale; h.z *= scale; h.w *= scale;
    if (relu) {
        h.x = fmaxf(h.x, 0.f); h.y = fmaxf(h.y, 0.f);
        h.z = fmaxf(h.z, 0.f); h.w = fmaxf(h.w, 0.f);
    }
    *(float4*)(outp + (size_t)n * DE + lane * 4) = h;
}

// --------------------------------------------------------------- classifier
// out = relu(h2 @ cw1^T + cb1) @ cw2^T + cb2 ; 32 nodes per block
__global__ __launch_bounds__(256) void k_classifier(const float* __restrict__ h2,
                                                    const float* __restrict__ cw1,
                                                    const float* __restrict__ cb1,
                                                    const float* __restrict__ cw2,
                                                    const float* __restrict__ cb2,
                                                    float* __restrict__ outp) {
    __shared__ float hs[32][260];   // +4 pad: <=4-way LDS conflicts
    __shared__ float hid[DF][32];   // [f][m] for conflict-free phase 2
    int m0 = blockIdx.x * 32;
    int t = threadIdx.x;
    // load 32x256 h2 tile
    for (int i = t; i < 32 * 64; i += 256) {          // 64 float4 per row
        int row = i >> 6;
        int c = (i & 63) * 4;
        float4 v = {0.f, 0.f, 0.f, 0.f};
        if (m0 + row < NN) v = *(const float4*)(h2 + (size_t)(m0 + row) * DE + c);
        hs[row][c + 0] = v.x; hs[row][c + 1] = v.y;
        hs[row][c + 2] = v.z; hs[row][c + 3] = v.w;
    }
    __syncthreads();
    // hidden: thread t -> node m = t&31, f = (t>>5) + 8j, j=0..15
    int m = t & 31;
    int fb = t >> 5;
    float acc[16];
#pragma unroll
    for (int j = 0; j < 16; ++j) acc[j] = cb1[fb + 8 * j];
    for (int k = 0; k < DE; k += 4) {
        float4 hv = *(const float4*)&hs[m][k];
#pragma unroll
        for (int j = 0; j < 16; ++j) {
            int f = fb + 8 * j;
            float4 w = *(const float4*)(cw1 + (size_t)f * DE + k);
            acc[j] += hv.x * w.x + hv.y * w.y + hv.z * w.z + hv.w * w.w;
        }
    }
#pragma unroll
    for (int j = 0; j < 16; ++j) hid[fb + 8 * j][m] = fmaxf(acc[j], 0.f);
    __syncthreads();
    // output: 32 nodes x 4 classes = 128 values
    if (t < 32 * NC) {
        int m2 = t >> 2, c = t & 3;
        float a = cb2[c];
#pragma unroll 8
        for (int f = 0; f < DF; ++f) a += hid[f][m2] * cw2[c * DF + f];
        if (m0 + m2 < NN) outp[(size_t)(m0 + m2) * NC + c] = a;
    }
}

// ------------------------------------------------------------------ mask copy
__global__ __launch_bounds__(256) void k_mask(const unsigned char* __restrict__ m8,
                                              float* __restrict__ o) {
    int i = blockIdx.x * 256 + threadIdx.x;
    if (i >= NN) return;
    // discriminate storage: bool bytes (m8[1]!=0 for all-true) vs int32/float32
    bool bytes = (m8[1] != 0);
    float v;
    if (bytes) v = (m8[i] != 0) ? 1.0f : 0.0f;
    else       v = (((const int*)m8)[i] != 0) ? 1.0f : 0.0f;
    o[i] = v;
}

// ------------------------------------------------------------------- launcher
extern "C" void kernel_launch(void* const* d_in, const int* in_sizes, int n_in,
                              void* d_out, int out_size, void* d_ws, size_t ws_size,
                              hipStream_t stream) {
    const float* x   = (const float*)d_in[0];
    const int*   ei  = (const int*)d_in[1];
    const void*  msk = d_in[2];
    const float* w1l = (const float*)d_in[3];
    const float* b1l = (const float*)d_in[4];
    const float* w1r = (const float*)d_in[5];
    const float* w2l = (const float*)d_in[6];
    const float* b2l = (const float*)d_in[7];
    const float* w2r = (const float*)d_in[8];
    const float* cw1 = (const float*)d_in[9];
    const float* cb1 = (const float*)d_in[10];
    const float* cw2 = (const float*)d_in[11];
    const float* cb2 = (const float*)d_in[12];

    float* out        = (float*)d_out;
    float* out_logits = out;                              // [N,4]
    float* out_mask   = out + (size_t)NN * NC;            // [N,1]
    float* h2         = out + (size_t)NN * NC + NN;       // [N,256]

    char* wp = (char*)d_ws;
    auto alloc = [&](size_t bytes) -> void* {
        void* p = (void*)wp;
        wp += (bytes + 255) & ~(size_t)255;
        return p;
    };
    int* counters = (int*)alloc((size_t)2 * NN * 4);  // deg | cnt2 (one memset)
    int* deg  = counters;
    int* cnt2 = counters + NN;
    int* rowptr  = (int*)alloc((size_t)(NN + 1) * 4);
    int* partial = (int*)alloc(256 * 4);
    int* poff    = (int*)alloc(256 * 4);
    int* col     = (int*)alloc((size_t)NE * 4);
    float* yl = (float*)alloc((size_t)NN * DE * 4);
    float* yr = (float*)alloc((size_t)NN * DE * 4);
    float* h1 = (float*)alloc((size_t)NN * DE * 4);

    const int* srcp = ei;
    const int* dstp = ei + NE;

    hipMemsetAsync(counters, 0, (size_t)2 * NN * 4, stream);
    k_degree<<<(NE + 255) / 256, 256, 0, stream>>>(dstp, deg);
    int nb = (NN + 255) / 256;  // 196
    k_scan1<<<nb, 256, 0, stream>>>(deg, partial);
    k_scan2<<<1, 256, 0, stream>>>(partial, poff, nb);
    k_scan3<<<nb, 256, 0, stream>>>(deg, poff, rowptr);
    k_scatter<<<(NE + 255) / 256, 256, 0, stream>>>(srcp, dstp, rowptr, cnt2, col);

    dim3 gg(DE / 64, (NN + 63) / 64);  // (4, 782)
    // layer 1: y = x @ w^T   (K=300)
    k_gemm<<<gg, 256, 0, stream>>>(x, w1l, yl, NN, KV, DE);
    k_gemm<<<gg, 256, 0, stream>>>(x, w1r, yr, NN, KV, DE);
    k_aggnorm<<<NN / 4, 256, 0, stream>>>(yl, yr, b1l, rowptr, col, h1, 1);
    // layer 2 (K=256)
    k_gemm<<<gg, 256, 0, stream>>>(h1, w2l, yl, NN, DE, DE);
    k_gemm<<<gg, 256, 0, stream>>>(h1, w2r, yr, NN, DE, DE);
    k_aggnorm<<<NN / 4, 256, 0, stream>>>(yl, yr, b2l, rowptr, col, h2, 0);
    // classifier + mask
    k_classifier<<<(NN + 31) / 32, 256, 0, stream>>>(h2, cw1, cb1, cw2, cb2, out_logits);
    k_mask<<<(NN + 255) / 256, 256, 0, stream>>>((const unsigned char*)msk, out_mask);
}

// Round 2
// 535.944 us; speedup vs baseline: 2.0209x; 2.0209x over previous
//
#include <hip/hip_runtime.h>

constexpr int NN = 50000;   // nodes
constexpr int MP = 50048;   // padded to 391*128
constexpr int NE = 800000;  // edges
constexpr int KV = 300;     // vocab / in_dim
constexpr int KP1 = 320;    // padded K for layer 1
constexpr int DE = 256;     // embed
constexpr int DF = 128;     // fc dim
constexpr int NC = 4;       // classes

typedef __attribute__((ext_vector_type(8))) short bf16x8;
typedef __attribute__((ext_vector_type(4))) float f32x4;

__device__ inline float b2f(ushort u) { return __uint_as_float((uint)u << 16); }
__device__ inline ushort f2b(float f) {
    uint u = __float_as_uint(f);
    u += 0x7fffu + ((u >> 16) & 1u);   // RNE (finite inputs only)
    return (ushort)(u >> 16);
}
__device__ inline void gload_lds16(const void* g, void* l) {
    __builtin_amdgcn_global_load_lds(
        (const __attribute__((address_space(1))) void*)g,
        (__attribute__((address_space(3))) void*)l, 16, 0, 0);
}

// ------------------------------------------------------------------ CSR build
__global__ __launch_bounds__(256) void k_degree(const int* __restrict__ dst,
                                                int* __restrict__ deg) {
    int e = blockIdx.x * 256 + threadIdx.x;
    if (e < NE) atomicAdd(&deg[dst[e]], 1);
}

__global__ __launch_bounds__(256) void k_scan1(const int* __restrict__ deg,
                                               int* __restrict__ partial) {
    __shared__ int sd[256];
    int t = threadIdx.x;
    int n = blockIdx.x * 256 + t;
    sd[t] = (n < NN) ? deg[n] : 0;
    __syncthreads();
    for (int off = 128; off > 0; off >>= 1) {
        if (t < off) sd[t] += sd[t + off];
        __syncthreads();
    }
    if (t == 0) partial[blockIdx.x] = sd[0];
}

__global__ __launch_bounds__(256) void k_scan2(const int* __restrict__ partial,
                                               int* __restrict__ poff, int nb) {
    __shared__ int sd[256];
    int t = threadIdx.x;
    int v = (t < nb) ? partial[t] : 0;
    sd[t] = v;
    __syncthreads();
    for (int off = 1; off < 256; off <<= 1) {
        int x = (t >= off) ? sd[t - off] : 0;
        __syncthreads();
        sd[t] += x;
        __syncthreads();
    }
    poff[t] = sd[t] - v;
}

__global__ __launch_bounds__(256) void k_scan3(const int* __restrict__ deg,
                                               const int* __restrict__ poff,
                                               int* __restrict__ rowptr) {
    __shared__ int sd[256];
    int t = threadIdx.x;
    int n = blockIdx.x * 256 + t;
    int v = (n < NN) ? deg[n] : 0;
    sd[t] = v;
    __syncthreads();
    for (int off = 1; off < 256; off <<= 1) {
        int x = (t >= off) ? sd[t - off] : 0;
        __syncthreads();
        sd[t] += x;
        __syncthreads();
    }
    if (n < NN) rowptr[n] = poff[blockIdx.x] + sd[t] - v;
    if (blockIdx.x == 0 && t == 0) rowptr[NN] = NE;
}

__global__ __launch_bounds__(256) void k_scatter(const int* __restrict__ src,
                                                 const int* __restrict__ dst,
                                                 const int* __restrict__ rowptr,
                                                 int* __restrict__ cnt2,
                                                 int* __restrict__ col) {
    int e = blockIdx.x * 256 + threadIdx.x;
    if (e < NE) {
        int d = dst[e];
        int p = rowptr[d] + atomicAdd(&cnt2[d], 1);
        col[p] = src[e];
    }
}

// ------------------------------------------------------- fp32 -> bf16 convert
// x [NN][300] -> xb [MP][320] (zero padded rows/cols)
__global__ __launch_bounds__(256) void k_cvt_x(const float* __restrict__ x,
                                               ushort* __restrict__ xb) {
    int i = blockIdx.x * 256 + threadIdx.x;
    if (i >= MP * (KP1 / 8)) return;
    int row = i / (KP1 / 8);
    int kb = (i % (KP1 / 8)) * 8;
    float f[8] = {0.f, 0.f, 0.f, 0.f, 0.f, 0.f, 0.f, 0.f};
    if (row < NN) {
        const float* s = x + (size_t)row * KV + kb;
        if (kb + 8 <= KV) {
            float4 v0 = *(const float4*)s;
            float4 v1 = *(const float4*)(s + 4);
            f[0] = v0.x; f[1] = v0.y; f[2] = v0.z; f[3] = v0.w;
            f[4] = v1.x; f[5] = v1.y; f[6] = v1.z; f[7] = v1.w;
        } else {
#pragma unroll
            for (int j = 0; j < 8; ++j)
                if (kb + j < KV) f[j] = s[j];
        }
    }
    ushort v[8];
#pragma unroll
    for (int j = 0; j < 8; ++j) v[j] = f2b(f[j]);
    uint4 pk;
    pk.x = (uint)v[0] | ((uint)v[1] << 16);
    pk.y = (uint)v[2] | ((uint)v[3] << 16);
    pk.z = (uint)v[4] | ((uint)v[5] << 16);
    pk.w = (uint)v[6] | ((uint)v[7] << 16);
    *(uint4*)(xb + (size_t)row * KP1 + kb) = pk;
}

// generic weight convert: w [rows][Kin] fp32 -> o [rows][KP] bf16 (k zero-pad)
__global__ __launch_bounds__(256) void k_cvt_w(const float* __restrict__ w,
                                               ushort* __restrict__ o,
                                               int rows, int Kin, int KPr) {
    int i = blockIdx.x * 256 + threadIdx.x;
    if (i >= rows * (KPr / 8)) return;
    int row = i / (KPr / 8);
    int kb = (i % (KPr / 8)) * 8;
    const float* s = w + (size_t)row * Kin + kb;
    float f[8] = {0.f, 0.f, 0.f, 0.f, 0.f, 0.f, 0.f, 0.f};
    if (kb + 8 <= Kin) {
        float4 v0 = *(const float4*)s;
        float4 v1 = *(const float4*)(s + 4);
        f[0] = v0.x; f[1] = v0.y; f[2] = v0.z; f[3] = v0.w;
        f[4] = v1.x; f[5] = v1.y; f[6] = v1.z; f[7] = v1.w;
    } else {
#pragma unroll
        for (int j = 0; j < 8; ++j)
            if (kb + j < Kin) f[j] = s[j];
    }
    ushort v[8];
#pragma unroll
    for (int j = 0; j < 8; ++j) v[j] = f2b(f[j]);
    uint4 pk;
    pk.x = (uint)v[0] | ((uint)v[1] << 16);
    pk.y = (uint)v[2] | ((uint)v[3] << 16);
    pk.z = (uint)v[4] | ((uint)v[5] << 16);
    pk.w = (uint)v[6] | ((uint)v[7] << 16);
    *(uint4*)(o + (size_t)row * KPr + kb) = pk;
}

// -------------------------------------------------------------- bf16 MFMA GEMM
// C[M,Nc](bf16) = A[M,KPr] @ B[Nc,KPr]^T  (+bias, relu optional)
// 128x128 tile, 4 waves (2x2 of 64x64), BK=32, global_load_lds staging.
__global__ __launch_bounds__(256) void k_mgemm(const ushort* __restrict__ A,
                                               const ushort* __restrict__ B,
                                               ushort* __restrict__ C,
                                               int KPr, int Nst,
                                               const float* __restrict__ bias,
                                               int relu) {
    __shared__ __align__(16) ushort As[128 * 32];
    __shared__ __align__(16) ushort Bs[128 * 32];
    const int t = threadIdx.x;
    const int bn = blockIdx.x * 128;
    const int bm = blockIdx.y * 128;
    const int w = t >> 6;
    const int lane = t & 63;
    const int wr = (w >> 1) * 64, wc = (w & 1) * 64;
    const int fr = lane & 15;          // fragment row (A) / col-row (B)
    const int fk = (lane >> 4) * 8;    // fragment k offset (8 contiguous)
    const int drow = (lane >> 4) * 4;  // C/D row base
    const int dcol = lane & 15;        // C/D col

    f32x4 acc[4][4];
#pragma unroll
    for (int m = 0; m < 4; ++m)
#pragma unroll
        for (int n = 0; n < 4; ++n) acc[m][n] = (f32x4){0.f, 0.f, 0.f, 0.f};

    const int arow = t >> 2;           // 0..63
    const int aoff = (t & 3) * 8;      // k elements
    const ushort* Ab = A + (size_t)(bm + arow) * KPr + aoff;
    const ushort* Bb = B + (size_t)(bn + arow) * KPr + aoff;
    ushort* Al = As + t * 8;
    ushort* Bl = Bs + t * 8;

    for (int k0 = 0; k0 < KPr; k0 += 32) {
        gload_lds16(Ab + k0, Al);
        gload_lds16(Ab + (size_t)64 * KPr + k0, Al + 64 * 32);
        gload_lds16(Bb + k0, Bl);
        gload_lds16(Bb + (size_t)64 * KPr + k0, Bl + 64 * 32);
        __syncthreads();
        bf16x8 af[4], bfr[4];
#pragma unroll
        for (int m = 0; m < 4; ++m)
            af[m] = *(const bf16x8*)(As + (wr + 16 * m + fr) * 32 + fk);
#pragma unroll
        for (int n = 0; n < 4; ++n)
            bfr[n] = *(const bf16x8*)(Bs + (wc + 16 * n + fr) * 32 + fk);
#pragma unroll
        for (int m = 0; m < 4; ++m)
#pragma unroll
            for (int n = 0; n < 4; ++n)
                acc[m][n] = __builtin_amdgcn_mfma_f32_16x16x32_bf16(
                    af[m], bfr[n], acc[m][n], 0, 0, 0);
        __syncthreads();
    }
#pragma unroll
    for (int m = 0; m < 4; ++m) {
        int gr0 = bm + wr + 16 * m + drow;
#pragma unroll
        for (int n = 0; n < 4; ++n) {
            int gc = bn + wc + 16 * n + dcol;
            float bv = bias ? bias[gc] : 0.f;
#pragma unroll
            for (int r = 0; r < 4; ++r) {
                float v = acc[m][n][r] + bv;
                if (relu) v = fmaxf(v, 0.f);
                C[(size_t)(gr0 + r) * Nst + gc] = f2b(v);
            }
        }
    }
}

// --------------------------------------------------- aggregate + norm (+relu)
// Cmat [MP][512] bf16: cols 0..255 = y_l, 256..511 = y_r. One wave per node.
__global__ __launch_bounds__(256) void k_aggnorm(const ushort* __restrict__ Cmat,
                                                 const float* __restrict__ bias,
                                                 const int* __restrict__ rowptr,
                                                 const int* __restrict__ col,
                                                 float* __restrict__ outf,
                                                 ushort* __restrict__ outb,
                                                 int relu) {
    int wave = threadIdx.x >> 6;
    int lane = threadIdx.x & 63;
    int n = blockIdx.x * 4 + wave;
    if (n >= NN) return;
    int beg = rowptr[n], end = rowptr[n + 1];
    float ax = 0.f, ay = 0.f, az = 0.f, aw = 0.f;
    for (int e = beg; e < end; ++e) {
        int s = col[e];
        ushort4 v = *(const ushort4*)(Cmat + (size_t)s * 512 + lane * 4);
        ax += b2f(v.x); ay += b2f(v.y); az += b2f(v.z); aw += b2f(v.w);
    }
    int d = end - beg;
    float inv = 1.0f / (float)(d > 1 ? d : 1);
    ushort4 rv = *(const ushort4*)(Cmat + (size_t)n * 512 + 256 + lane * 4);
    float4 b = *(const float4*)(bias + lane * 4);
    float hx = ax * inv + b.x + b2f(rv.x);
    float hy = ay * inv + b.y + b2f(rv.y);
    float hz = az * inv + b.z + b2f(rv.z);
    float hw = aw * inv + b.w + b2f(rv.w);
    float ss = hx * hx + hy * hy + hz * hz + hw * hw;
#pragma unroll
    for (int off = 32; off > 0; off >>= 1) ss += __shfl_xor(ss, off, 64);
    float scale = 1.0f / fmaxf(sqrtf(ss), 1e-12f);
    hx *= scale; hy *= scale; hz *= scale; hw *= scale;
    if (relu) {
        hx = fmaxf(hx, 0.f); hy = fmaxf(hy, 0.f);
        hz = fmaxf(hz, 0.f); hw = fmaxf(hw, 0.f);
    }
    if (outf) {
        float4 o = make_float4(hx, hy, hz, hw);
        *(float4*)(outf + (size_t)n * DE + lane * 4) = o;
    }
    ushort4 ob;
    ob.x = f2b(hx); ob.y = f2b(hy); ob.z = f2b(hz); ob.w = f2b(hw);
    *(ushort4*)(outb + (size_t)n * DE + lane * 4) = ob;
}

// ---------------------------------------------------- classifier phase 2
// out[n][c] = sum_f hid_bf[n][f] * cw2[c][f] + cb2[c]; one wave per node.
__global__ __launch_bounds__(256) void k_out(const ushort* __restrict__ hid,
                                             const float* __restrict__ cw2,
                                             const float* __restrict__ cb2,
                                             float* __restrict__ outp) {
    int wave = threadIdx.x >> 6;
    int lane = threadIdx.x & 63;
    int n = blockIdx.x * 4 + wave;
    if (n >= NN) return;
    uint hv = *(const uint*)(hid + (size_t)n * DF + lane * 2);
    float h0 = b2f((ushort)(hv & 0xffff));
    float h1 = b2f((ushort)(hv >> 16));
    float p0 = h0 * cw2[0 * DF + 2 * lane] + h1 * cw2[0 * DF + 2 * lane + 1];
    float p1 = h0 * cw2[1 * DF + 2 * lane] + h1 * cw2[1 * DF + 2 * lane + 1];
    float p2 = h0 * cw2[2 * DF + 2 * lane] + h1 * cw2[2 * DF + 2 * lane + 1];
    float p3 = h0 * cw2[3 * DF + 2 * lane] + h1 * cw2[3 * DF + 2 * lane + 1];
#pragma unroll
    for (int off = 32; off > 0; off >>= 1) {
        p0 += __shfl_xor(p0, off, 64);
        p1 += __shfl_xor(p1, off, 64);
        p2 += __shfl_xor(p2, off, 64);
        p3 += __shfl_xor(p3, off, 64);
    }
    if (lane == 0) {
        outp[(size_t)n * NC + 0] = p0 + cb2[0];
        outp[(size_t)n * NC + 1] = p1 + cb2[1];
        outp[(size_t)n * NC + 2] = p2 + cb2[2];
        outp[(size_t)n * NC + 3] = p3 + cb2[3];
    }
}

// ------------------------------------------------------------------ mask copy
__global__ __launch_bounds__(256) void k_mask(const unsigned char* __restrict__ m8,
                                              float* __restrict__ o) {
    int i = blockIdx.x * 256 + threadIdx.x;
    if (i >= NN) return;
    bool bytes = (m8[1] != 0);
    float v;
    if (bytes) v = (m8[i] != 0) ? 1.0f : 0.0f;
    else       v = (((const int*)m8)[i] != 0) ? 1.0f : 0.0f;
    o[i] = v;
}

// ------------------------------------------------------------------- launcher
extern "C" void kernel_launch(void* const* d_in, const int* in_sizes, int n_in,
                              void* d_out, int out_size, void* d_ws, size_t ws_size,
                              hipStream_t stream) {
    const float* x   = (const float*)d_in[0];
    const int*   ei  = (const int*)d_in[1];
    const void*  msk = d_in[2];
    const float* w1l = (const float*)d_in[3];
    const float* b1l = (const float*)d_in[4];
    const float* w1r = (const float*)d_in[5];
    const float* w2l = (const float*)d_in[6];
    const float* b2l = (const float*)d_in[7];
    const float* w2r = (const float*)d_in[8];
    const float* cw1 = (const float*)d_in[9];
    const float* cb1 = (const float*)d_in[10];
    const float* cw2 = (const float*)d_in[11];
    const float* cb2 = (const float*)d_in[12];

    float* out        = (float*)d_out;
    float* out_logits = out;                              // [N,4]
    float* out_mask   = out + (size_t)NN * NC;            // [N,1]
    float* h2f        = out + (size_t)NN * NC + NN;       // [N,256]

    char* wp = (char*)d_ws;
    auto alloc = [&](size_t bytes) -> void* {
        void* p = (void*)wp;
        wp += (bytes + 255) & ~(size_t)255;
        return p;
    };
    int* counters = (int*)alloc((size_t)2 * NN * 4);
    int* deg  = counters;
    int* cnt2 = counters + NN;
    int* rowptr  = (int*)alloc((size_t)(NN + 1) * 4);
    int* partial = (int*)alloc(256 * 4);
    int* poff    = (int*)alloc(256 * 4);
    int* col     = (int*)alloc((size_t)NE * 4);
    ushort* xb    = (ushort*)alloc((size_t)MP * KP1 * 2);
    ushort* wcat1 = (ushort*)alloc((size_t)512 * KP1 * 2);
    ushort* wcat2 = (ushort*)alloc((size_t)512 * DE * 2);
    ushort* cw1b  = (ushort*)alloc((size_t)DF * DE * 2);
    ushort* Cbuf  = (ushort*)alloc((size_t)MP * 512 * 2);  // reused both layers
    ushort* h1b   = (ushort*)alloc((size_t)MP * DE * 2);
    ushort* h2b   = (ushort*)alloc((size_t)MP * DE * 2);
    ushort* hidb  = (ushort*)alloc((size_t)MP * DF * 2);

    const int* srcp = ei;
    const int* dstp = ei + NE;

    // CSR + conversions
    hipMemsetAsync(counters, 0, (size_t)2 * NN * 4, stream);
    k_degree<<<(NE + 255) / 256, 256, 0, stream>>>(dstp, deg);
    int nb = (NN + 255) / 256;  // 196
    k_scan1<<<nb, 256, 0, stream>>>(deg, partial);
    k_scan2<<<1, 256, 0, stream>>>(partial, poff, nb);
    k_scan3<<<nb, 256, 0, stream>>>(deg, poff, rowptr);
    k_scatter<<<(NE + 255) / 256, 256, 0, stream>>>(srcp, dstp, rowptr, cnt2, col);

    k_cvt_x<<<(MP * (KP1 / 8) + 255) / 256, 256, 0, stream>>>(x, xb);
    k_cvt_w<<<(256 * (KP1 / 8) + 255) / 256, 256, 0, stream>>>(w1l, wcat1, 256, KV, KP1);
    k_cvt_w<<<(256 * (KP1 / 8) + 255) / 256, 256, 0, stream>>>(w1r, wcat1 + (size_t)256 * KP1, 256, KV, KP1);
    k_cvt_w<<<(256 * (DE / 8) + 255) / 256, 256, 0, stream>>>(w2l, wcat2, 256, DE, DE);
    k_cvt_w<<<(256 * (DE / 8) + 255) / 256, 256, 0, stream>>>(w2r, wcat2 + (size_t)256 * DE, 256, DE, DE);
    k_cvt_w<<<(DF * (DE / 8) + 255) / 256, 256, 0, stream>>>(cw1, cw1b, DF, DE, DE);

    dim3 g1(512 / 128, MP / 128);  // (4, 391)
    k_mgemm<<<g1, 256, 0, stream>>>(xb, wcat1, Cbuf, KP1, 512, nullptr, 0);
    k_aggnorm<<<NN / 4, 256, 0, stream>>>(Cbuf, b1l, rowptr, col, nullptr, h1b, 1);
    k_mgemm<<<g1, 256, 0, stream>>>(h1b, wcat2, Cbuf, DE, 512, nullptr, 0);
    k_aggnorm<<<NN / 4, 256, 0, stream>>>(Cbuf, b2l, rowptr, col, h2f, h2b, 0);

    dim3 g2(DF / 128, MP / 128);   // (1, 391)
    k_mgemm<<<g2, 256, 0, stream>>>(h2b, cw1b, hidb, DE, DF, cb1, 1);
    k_out<<<(NN + 3) / 4, 256, 0, stream>>>(hidb, cw2, cb2, out_logits);
    k_mask<<<(NN + 255) / 256, 256, 0, stream>>>((const unsigned char*)msk, out_mask);
}

// Round 3
// 468.030 us; speedup vs baseline: 2.3142x; 1.1451x over previous
//
#include <hip/hip_runtime.h>

constexpr int NN = 50000;   // nodes
constexpr int MP = 50048;   // padded to 391*128
constexpr int NE = 800000;  // edges
constexpr int KV = 300;     // vocab / in_dim
constexpr int KP1 = 320;    // padded K for layer 1 (5 x BK64)
constexpr int DE = 256;     // embed
constexpr int DF = 128;     // fc dim
constexpr int NC = 4;       // classes

typedef __attribute__((ext_vector_type(8))) short bf16x8;
typedef __attribute__((ext_vector_type(4))) float f32x4;

__device__ inline float b2f(ushort u) { return __uint_as_float((uint)u << 16); }
__device__ inline ushort f2b(float f) {
    uint u = __float_as_uint(f);
    u += 0x7fffu + ((u >> 16) & 1u);   // RNE (finite inputs only)
    return (ushort)(u >> 16);
}
__device__ inline void gload_lds16(const void* g, void* l) {
    __builtin_amdgcn_global_load_lds(
        (const __attribute__((address_space(1))) void*)g,
        (__attribute__((address_space(3))) void*)l, 16, 0, 0);
}

// ------------------------------------------------------------------ CSR build
__global__ __launch_bounds__(256) void k_degree(const int* __restrict__ dst,
                                                int* __restrict__ deg) {
    int e = blockIdx.x * 256 + threadIdx.x;
    if (e < NE) atomicAdd(&deg[dst[e]], 1);
}

__global__ __launch_bounds__(256) void k_scan1(const int* __restrict__ deg,
                                               int* __restrict__ partial) {
    __shared__ int sd[256];
    int t = threadIdx.x;
    int n = blockIdx.x * 256 + t;
    sd[t] = (n < NN) ? deg[n] : 0;
    __syncthreads();
    for (int off = 128; off > 0; off >>= 1) {
        if (t < off) sd[t] += sd[t + off];
        __syncthreads();
    }
    if (t == 0) partial[blockIdx.x] = sd[0];
}

__global__ __launch_bounds__(256) void k_scan2(const int* __restrict__ partial,
                                               int* __restrict__ poff, int nb) {
    __shared__ int sd[256];
    int t = threadIdx.x;
    int v = (t < nb) ? partial[t] : 0;
    sd[t] = v;
    __syncthreads();
    for (int off = 1; off < 256; off <<= 1) {
        int x = (t >= off) ? sd[t - off] : 0;
        __syncthreads();
        sd[t] += x;
        __syncthreads();
    }
    poff[t] = sd[t] - v;
}

__global__ __launch_bounds__(256) void k_scan3(const int* __restrict__ deg,
                                               const int* __restrict__ poff,
                                               int* __restrict__ rowptr) {
    __shared__ int sd[256];
    int t = threadIdx.x;
    int n = blockIdx.x * 256 + t;
    int v = (n < NN) ? deg[n] : 0;
    sd[t] = v;
    __syncthreads();
    for (int off = 1; off < 256; off <<= 1) {
        int x = (t >= off) ? sd[t - off] : 0;
        __syncthreads();
        sd[t] += x;
        __syncthreads();
    }
    if (n < NN) rowptr[n] = poff[blockIdx.x] + sd[t] - v;
    if (blockIdx.x == 0 && t == 0) rowptr[NN] = NE;
}

__global__ __launch_bounds__(256) void k_scatter(const int* __restrict__ src,
                                                 const int* __restrict__ dst,
                                                 const int* __restrict__ rowptr,
                                                 int* __restrict__ cnt2,
                                                 int* __restrict__ col) {
    int e = blockIdx.x * 256 + threadIdx.x;
    if (e < NE) {
        int d = dst[e];
        int p = rowptr[d] + atomicAdd(&cnt2[d], 1);
        col[p] = src[e];
    }
}

// ------------------------------------------------------- fp32 -> bf16 convert
__global__ __launch_bounds__(256) void k_cvt_x(const float* __restrict__ x,
                                               ushort* __restrict__ xb) {
    int i = blockIdx.x * 256 + threadIdx.x;
    if (i >= MP * (KP1 / 8)) return;
    int row = i / (KP1 / 8);
    int kb = (i % (KP1 / 8)) * 8;
    float f[8] = {0.f, 0.f, 0.f, 0.f, 0.f, 0.f, 0.f, 0.f};
    if (row < NN) {
        const float* s = x + (size_t)row * KV + kb;
        if (kb + 8 <= KV) {
            float4 v0 = *(const float4*)s;
            float4 v1 = *(const float4*)(s + 4);
            f[0] = v0.x; f[1] = v0.y; f[2] = v0.z; f[3] = v0.w;
            f[4] = v1.x; f[5] = v1.y; f[6] = v1.z; f[7] = v1.w;
        } else {
#pragma unroll
            for (int j = 0; j < 8; ++j)
                if (kb + j < KV) f[j] = s[j];
        }
    }
    ushort v[8];
#pragma unroll
    for (int j = 0; j < 8; ++j) v[j] = f2b(f[j]);
    uint4 pk;
    pk.x = (uint)v[0] | ((uint)v[1] << 16);
    pk.y = (uint)v[2] | ((uint)v[3] << 16);
    pk.z = (uint)v[4] | ((uint)v[5] << 16);
    pk.w = (uint)v[6] | ((uint)v[7] << 16);
    *(uint4*)(xb + (size_t)row * KP1 + kb) = pk;
}

__global__ __launch_bounds__(256) void k_cvt_w(const float* __restrict__ w,
                                               ushort* __restrict__ o,
                                               int rows, int Kin, int KPr) {
    int i = blockIdx.x * 256 + threadIdx.x;
    if (i >= rows * (KPr / 8)) return;
    int row = i / (KPr / 8);
    int kb = (i % (KPr / 8)) * 8;
    const float* s = w + (size_t)row * Kin + kb;
    float f[8] = {0.f, 0.f, 0.f, 0.f, 0.f, 0.f, 0.f, 0.f};
    if (kb + 8 <= Kin) {
        float4 v0 = *(const float4*)s;
        float4 v1 = *(const float4*)(s + 4);
        f[0] = v0.x; f[1] = v0.y; f[2] = v0.z; f[3] = v0.w;
        f[4] = v1.x; f[5] = v1.y; f[6] = v1.z; f[7] = v1.w;
    } else {
#pragma unroll
        for (int j = 0; j < 8; ++j)
            if (kb + j < Kin) f[j] = s[j];
    }
    ushort v[8];
#pragma unroll
    for (int j = 0; j < 8; ++j) v[j] = f2b(f[j]);
    uint4 pk;
    pk.x = (uint)v[0] | ((uint)v[1] << 16);
    pk.y = (uint)v[2] | ((uint)v[3] << 16);
    pk.z = (uint)v[4] | ((uint)v[5] << 16);
    pk.w = (uint)v[6] | ((uint)v[7] << 16);
    *(uint4*)(o + (size_t)row * KPr + kb) = pk;
}

// -------------------------------------------------------------- bf16 MFMA GEMM
// C[M,Nc](bf16) = A[M,KPr] @ B[Nc,KPr]^T  (+bias, relu optional)
// 128x128 tile, 4 waves (2x2 of 64x64), BK=64, global_load_lds staging with
// 16B-block XOR swizzle: stored[row][b] = global[row][b ^ (row&7)] so that
// fragment ds_read_b128 spreads across 8 bank-quads (2-way = free).
__global__ __launch_bounds__(256) void k_mgemm(const ushort* __restrict__ A,
                                               const ushort* __restrict__ B,
                                               ushort* __restrict__ C,
                                               int KPr, int Nst,
                                               const float* __restrict__ bias,
                                               int relu) {
    __shared__ __align__(16) ushort As[128 * 64];
    __shared__ __align__(16) ushort Bs[128 * 64];
    const int t = threadIdx.x;
    const int bn = blockIdx.x * 128;
    const int bm = blockIdx.y * 128;
    const int w = t >> 6;
    const int lane = t & 63;
    const int wr = (w >> 1) * 64, wc = (w & 1) * 64;
    const int fr = lane & 15;          // fragment row
    const int fg = lane >> 4;          // k-group 0..3 (8 elems each)
    const int drow = (lane >> 4) * 4;  // C/D row base
    const int dcol = lane & 15;        // C/D col

    f32x4 acc[4][4];
#pragma unroll
    for (int m = 0; m < 4; ++m)
#pragma unroll
        for (int n = 0; n < 4; ++n) acc[m][n] = (f32x4){0.f, 0.f, 0.f, 0.f};

    // staging: lane covers row (w*32 + j*8 + (lane>>3)), 16B block (lane&7),
    // fetching global block ((lane&7) ^ (lane>>3))  [row&7 == lane>>3]
    const int srow = lane >> 3;        // 0..7
    const int sblk = (lane & 7) ^ srow;
    const ushort* Ab = A + (size_t)(bm + w * 32 + srow) * KPr + sblk * 8;
    const ushort* Bb = B + (size_t)(bn + w * 32 + srow) * KPr + sblk * 8;
    ushort* Al = As + w * 2048 + lane * 8;
    ushort* Bl = Bs + w * 2048 + lane * 8;

    for (int k0 = 0; k0 < KPr; k0 += 64) {
#pragma unroll
        for (int j = 0; j < 4; ++j) {
            gload_lds16(Ab + k0 + (size_t)j * 8 * KPr, Al + j * 512);
            gload_lds16(Bb + k0 + (size_t)j * 8 * KPr, Bl + j * 512);
        }
        __syncthreads();
#pragma unroll
        for (int ks = 0; ks < 2; ++ks) {
            bf16x8 af[4], bfr[4];
#pragma unroll
            for (int m = 0; m < 4; ++m) {
                int row = wr + 16 * m + fr;
                int blk = (fg + 4 * ks) ^ (row & 7);
                af[m] = *(const bf16x8*)(As + row * 64 + blk * 8);
            }
#pragma unroll
            for (int n = 0; n < 4; ++n) {
                int row = wc + 16 * n + fr;
                int blk = (fg + 4 * ks) ^ (row & 7);
                bfr[n] = *(const bf16x8*)(Bs + row * 64 + blk * 8);
            }
#pragma unroll
            for (int m = 0; m < 4; ++m)
#pragma unroll
                for (int n = 0; n < 4; ++n)
                    acc[m][n] = __builtin_amdgcn_mfma_f32_16x16x32_bf16(
                        af[m], bfr[n], acc[m][n], 0, 0, 0);
        }
        __syncthreads();
    }
#pragma unroll
    for (int m = 0; m < 4; ++m) {
        int gr0 = bm + wr + 16 * m + drow;
#pragma unroll
        for (int n = 0; n < 4; ++n) {
            int gc = bn + wc + 16 * n + dcol;
            float bv = bias ? bias[gc] : 0.f;
#pragma unroll
            for (int r = 0; r < 4; ++r) {
                float v = acc[m][n][r] + bv;
                if (relu) v = fmaxf(v, 0.f);
                C[(size_t)(gr0 + r) * Nst + gc] = f2b(v);
            }
        }
    }
}

// --------------------------------------------------- aggregate + norm (+relu)
// Cmat [MP][512] bf16: cols 0..255 = y_l, 256..511 = y_r. One wave per node.
// 4-edge unroll for memory-level parallelism.
__global__ __launch_bounds__(256) void k_aggnorm(const ushort* __restrict__ Cmat,
                                                 const float* __restrict__ bias,
                                                 const int* __restrict__ rowptr,
                                                 const int* __restrict__ col,
                                                 float* __restrict__ outf,
                                                 ushort* __restrict__ outb,
                                                 int relu) {
    int wave = threadIdx.x >> 6;
    int lane = threadIdx.x & 63;
    int n = blockIdx.x * 4 + wave;
    if (n >= NN) return;
    int beg = rowptr[n], end = rowptr[n + 1];
    const ushort* base = Cmat + (size_t)lane * 4;
    float a0 = 0.f, a1 = 0.f, a2 = 0.f, a3 = 0.f;
    float c0 = 0.f, c1 = 0.f, c2 = 0.f, c3 = 0.f;
    int e = beg;
    for (; e + 4 <= end; e += 4) {
        int s0 = col[e], s1 = col[e + 1], s2 = col[e + 2], s3 = col[e + 3];
        ushort4 v0 = *(const ushort4*)(base + (size_t)s0 * 512);
        ushort4 v1 = *(const ushort4*)(base + (size_t)s1 * 512);
        ushort4 v2 = *(const ushort4*)(base + (size_t)s2 * 512);
        ushort4 v3 = *(const ushort4*)(base + (size_t)s3 * 512);
        a0 += b2f(v0.x); a1 += b2f(v0.y); a2 += b2f(v0.z); a3 += b2f(v0.w);
        c0 += b2f(v1.x); c1 += b2f(v1.y); c2 += b2f(v1.z); c3 += b2f(v1.w);
        a0 += b2f(v2.x); a1 += b2f(v2.y); a2 += b2f(v2.z); a3 += b2f(v2.w);
        c0 += b2f(v3.x); c1 += b2f(v3.y); c2 += b2f(v3.z); c3 += b2f(v3.w);
    }
    for (; e < end; ++e) {
        int s = col[e];
        ushort4 v = *(const ushort4*)(base + (size_t)s * 512);
        a0 += b2f(v.x); a1 += b2f(v.y); a2 += b2f(v.z); a3 += b2f(v.w);
    }
    a0 += c0; a1 += c1; a2 += c2; a3 += c3;
    int d = end - beg;
    float inv = 1.0f / (float)(d > 1 ? d : 1);
    ushort4 rv = *(const ushort4*)(Cmat + (size_t)n * 512 + 256 + lane * 4);
    float4 b = *(const float4*)(bias + lane * 4);
    float hx = a0 * inv + b.x + b2f(rv.x);
    float hy = a1 * inv + b.y + b2f(rv.y);
    float hz = a2 * inv + b.z + b2f(rv.z);
    float hw = a3 * inv + b.w + b2f(rv.w);
    float ss = hx * hx + hy * hy + hz * hz + hw * hw;
#pragma unroll
    for (int off = 32; off > 0; off >>= 1) ss += __shfl_xor(ss, off, 64);
    float scale = 1.0f / fmaxf(sqrtf(ss), 1e-12f);
    hx *= scale; hy *= scale; hz *= scale; hw *= scale;
    if (relu) {
        hx = fmaxf(hx, 0.f); hy = fmaxf(hy, 0.f);
        hz = fmaxf(hz, 0.f); hw = fmaxf(hw, 0.f);
    }
    if (outf) {
        float4 o = make_float4(hx, hy, hz, hw);
        *(float4*)(outf + (size_t)n * DE + lane * 4) = o;
    }
    ushort4 ob;
    ob.x = f2b(hx); ob.y = f2b(hy); ob.z = f2b(hz); ob.w = f2b(hw);
    *(ushort4*)(outb + (size_t)n * DE + lane * 4) = ob;
}

// ---------------------------------------------------- classifier phase 2
__global__ __launch_bounds__(256) void k_out(const ushort* __restrict__ hid,
                                             const float* __restrict__ cw2,
                                             const float* __restrict__ cb2,
                                             float* __restrict__ outp) {
    int wave = threadIdx.x >> 6;
    int lane = threadIdx.x & 63;
    int n = blockIdx.x * 4 + wave;
    if (n >= NN) return;
    uint hv = *(const uint*)(hid + (size_t)n * DF + lane * 2);
    float h0 = b2f((ushort)(hv & 0xffff));
    float h1 = b2f((ushort)(hv >> 16));
    float p0 = h0 * cw2[0 * DF + 2 * lane] + h1 * cw2[0 * DF + 2 * lane + 1];
    float p1 = h0 * cw2[1 * DF + 2 * lane] + h1 * cw2[1 * DF + 2 * lane + 1];
    float p2 = h0 * cw2[2 * DF + 2 * lane] + h1 * cw2[2 * DF + 2 * lane + 1];
    float p3 = h0 * cw2[3 * DF + 2 * lane] + h1 * cw2[3 * DF + 2 * lane + 1];
#pragma unroll
    for (int off = 32; off > 0; off >>= 1) {
        p0 += __shfl_xor(p0, off, 64);
        p1 += __shfl_xor(p1, off, 64);
        p2 += __shfl_xor(p2, off, 64);
        p3 += __shfl_xor(p3, off, 64);
    }
    if (lane == 0) {
        outp[(size_t)n * NC + 0] = p0 + cb2[0];
        outp[(size_t)n * NC + 1] = p1 + cb2[1];
        outp[(size_t)n * NC + 2] = p2 + cb2[2];
        outp[(size_t)n * NC + 3] = p3 + cb2[3];
    }
}

// ------------------------------------------------------------------ mask copy
__global__ __launch_bounds__(256) void k_mask(const unsigned char* __restrict__ m8,
                                              float* __restrict__ o) {
    int i = blockIdx.x * 256 + threadIdx.x;
    if (i >= NN) return;
    bool bytes = (m8[1] != 0);
    float v;
    if (bytes) v = (m8[i] != 0) ? 1.0f : 0.0f;
    else       v = (((const int*)m8)[i] != 0) ? 1.0f : 0.0f;
    o[i] = v;
}

// ------------------------------------------------------------------- launcher
extern "C" void kernel_launch(void* const* d_in, const int* in_sizes, int n_in,
                              void* d_out, int out_size, void* d_ws, size_t ws_size,
                              hipStream_t stream) {
    const float* x   = (const float*)d_in[0];
    const int*   ei  = (const int*)d_in[1];
    const void*  msk = d_in[2];
    const float* w1l = (const float*)d_in[3];
    const float* b1l = (const float*)d_in[4];
    const float* w1r = (const float*)d_in[5];
    const float* w2l = (const float*)d_in[6];
    const float* b2l = (const float*)d_in[7];
    const float* w2r = (const float*)d_in[8];
    const float* cw1 = (const float*)d_in[9];
    const float* cb1 = (const float*)d_in[10];
    const float* cw2 = (const float*)d_in[11];
    const float* cb2 = (const float*)d_in[12];

    float* out        = (float*)d_out;
    float* out_logits = out;                              // [N,4]
    float* out_mask   = out + (size_t)NN * NC;            // [N,1]
    float* h2f        = out + (size_t)NN * NC + NN;       // [N,256]

    char* wp = (char*)d_ws;
    auto alloc = [&](size_t bytes) -> void* {
        void* p = (void*)wp;
        wp += (bytes + 255) & ~(size_t)255;
        return p;
    };
    int* counters = (int*)alloc((size_t)2 * NN * 4);
    int* deg  = counters;
    int* cnt2 = counters + NN;
    int* rowptr  = (int*)alloc((size_t)(NN + 1) * 4);
    int* partial = (int*)alloc(256 * 4);
    int* poff    = (int*)alloc(256 * 4);
    int* col     = (int*)alloc((size_t)NE * 4);
    ushort* xb    = (ushort*)alloc((size_t)MP * KP1 * 2);
    ushort* wcat1 = (ushort*)alloc((size_t)512 * KP1 * 2);
    ushort* wcat2 = (ushort*)alloc((size_t)512 * DE * 2);
    ushort* cw1b  = (ushort*)alloc((size_t)DF * DE * 2);
    ushort* Cbuf  = (ushort*)alloc((size_t)MP * 512 * 2);
    ushort* h1b   = (ushort*)alloc((size_t)MP * DE * 2);
    ushort* h2b   = (ushort*)alloc((size_t)MP * DE * 2);
    ushort* hidb  = (ushort*)alloc((size_t)MP * DF * 2);

    const int* srcp = ei;
    const int* dstp = ei + NE;

    hipMemsetAsync(counters, 0, (size_t)2 * NN * 4, stream);
    k_degree<<<(NE + 255) / 256, 256, 0, stream>>>(dstp, deg);
    int nb = (NN + 255) / 256;  // 196
    k_scan1<<<nb, 256, 0, stream>>>(deg, partial);
    k_scan2<<<1, 256, 0, stream>>>(partial, poff, nb);
    k_scan3<<<nb, 256, 0, stream>>>(deg, poff, rowptr);
    k_scatter<<<(NE + 255) / 256, 256, 0, stream>>>(srcp, dstp, rowptr, cnt2, col);

    k_cvt_x<<<(MP * (KP1 / 8) + 255) / 256, 256, 0, stream>>>(x, xb);
    k_cvt_w<<<(256 * (KP1 / 8) + 255) / 256, 256, 0, stream>>>(w1l, wcat1, 256, KV, KP1);
    k_cvt_w<<<(256 * (KP1 / 8) + 255) / 256, 256, 0, stream>>>(w1r, wcat1 + (size_t)256 * KP1, 256, KV, KP1);
    k_cvt_w<<<(256 * (DE / 8) + 255) / 256, 256, 0, stream>>>(w2l, wcat2, 256, DE, DE);
    k_cvt_w<<<(256 * (DE / 8) + 255) / 256, 256, 0, stream>>>(w2r, wcat2 + (size_t)256 * DE, 256, DE, DE);
    k_cvt_w<<<(DF * (DE / 8) + 255) / 256, 256, 0, stream>>>(cw1, cw1b, DF, DE, DE);

    dim3 g1(512 / 128, MP / 128);  // (4, 391)
    k_mgemm<<<g1, 256, 0, stream>>>(xb, wcat1, Cbuf, KP1, 512, nullptr, 0);
    k_aggnorm<<<NN / 4, 256, 0, stream>>>(Cbuf, b1l, rowptr, col, nullptr, h1b, 1);
    k_mgemm<<<g1, 256, 0, stream>>>(h1b, wcat2, Cbuf, DE, 512, nullptr, 0);
    k_aggnorm<<<NN / 4, 256, 0, stream>>>(Cbuf, b2l, rowptr, col, h2f, h2b, 0);

    dim3 g2(DF / 128, MP / 128);   // (1, 391)
    k_mgemm<<<g2, 256, 0, stream>>>(h2b, cw1b, hidb, DE, DF, cb1, 1);
    k_out<<<(NN + 3) / 4, 256, 0, stream>>>(hidb, cw2, cb2, out_logits);
    k_mask<<<(NN + 255) / 256, 256, 0, stream>>>((const unsigned char*)msk, out_mask);
}

// Round 4
// 401.471 us; speedup vs baseline: 2.6978x; 1.1658x over previous
//
#include <hip/hip_runtime.h>

constexpr int NN = 50000;   // nodes
constexpr int MP = 50048;   // padded to 391*128
constexpr int NE = 800000;  // edges
constexpr int KV = 300;     // vocab / in_dim
constexpr int KP1 = 320;    // padded K for layer 1 (5 x BK64)
constexpr int DE = 256;     // embed
constexpr int DF = 128;     // fc dim
constexpr int NC = 4;       // classes

typedef __attribute__((ext_vector_type(8))) short bf16x8;
typedef __attribute__((ext_vector_type(4))) float f32x4;

__device__ inline float b2f(ushort u) { return __uint_as_float((uint)u << 16); }
__device__ inline ushort f2b(float f) {
    uint u = __float_as_uint(f);
    u += 0x7fffu + ((u >> 16) & 1u);   // RNE (finite inputs only)
    return (ushort)(u >> 16);
}
__device__ inline void gload_lds16(const void* g, void* l) {
    __builtin_amdgcn_global_load_lds(
        (const __attribute__((address_space(1))) void*)g,
        (__attribute__((address_space(3))) void*)l, 16, 0, 0);
}

// ------------------------------------------------------------------ CSR build
__global__ __launch_bounds__(256) void k_degree(const int* __restrict__ dst,
                                                int* __restrict__ deg) {
    int e = blockIdx.x * 256 + threadIdx.x;
    if (e < NE) atomicAdd(&deg[dst[e]], 1);
}

__global__ __launch_bounds__(256) void k_scan1(const int* __restrict__ deg,
                                               int* __restrict__ partial) {
    __shared__ int sd[256];
    int t = threadIdx.x;
    int n = blockIdx.x * 256 + t;
    sd[t] = (n < NN) ? deg[n] : 0;
    __syncthreads();
    for (int off = 128; off > 0; off >>= 1) {
        if (t < off) sd[t] += sd[t + off];
        __syncthreads();
    }
    if (t == 0) partial[blockIdx.x] = sd[0];
}

__global__ __launch_bounds__(256) void k_scan2(const int* __restrict__ partial,
                                               int* __restrict__ poff, int nb) {
    __shared__ int sd[256];
    int t = threadIdx.x;
    int v = (t < nb) ? partial[t] : 0;
    sd[t] = v;
    __syncthreads();
    for (int off = 1; off < 256; off <<= 1) {
        int x = (t >= off) ? sd[t - off] : 0;
        __syncthreads();
        sd[t] += x;
        __syncthreads();
    }
    poff[t] = sd[t] - v;
}

__global__ __launch_bounds__(256) void k_scan3(const int* __restrict__ deg,
                                               const int* __restrict__ poff,
                                               int* __restrict__ rowptr) {
    __shared__ int sd[256];
    int t = threadIdx.x;
    int n = blockIdx.x * 256 + t;
    int v = (n < NN) ? deg[n] : 0;
    sd[t] = v;
    __syncthreads();
    for (int off = 1; off < 256; off <<= 1) {
        int x = (t >= off) ? sd[t - off] : 0;
        __syncthreads();
        sd[t] += x;
        __syncthreads();
    }
    if (n < NN) rowptr[n] = poff[blockIdx.x] + sd[t] - v;
    if (blockIdx.x == 0 && t == 0) rowptr[NN] = NE;
}

__global__ __launch_bounds__(256) void k_scatter(const int* __restrict__ src,
                                                 const int* __restrict__ dst,
                                                 const int* __restrict__ rowptr,
                                                 int* __restrict__ cnt2,
                                                 int* __restrict__ col) {
    int e = blockIdx.x * 256 + threadIdx.x;
    if (e < NE) {
        int d = dst[e];
        int p = rowptr[d] + atomicAdd(&cnt2[d], 1);
        col[p] = src[e];
    }
}

// ------------------------------------------------------- fp32 -> bf16 convert
__global__ __launch_bounds__(256) void k_cvt_x(const float* __restrict__ x,
                                               ushort* __restrict__ xb) {
    int i = blockIdx.x * 256 + threadIdx.x;
    if (i >= MP * (KP1 / 8)) return;
    int row = i / (KP1 / 8);
    int kb = (i % (KP1 / 8)) * 8;
    float f[8] = {0.f, 0.f, 0.f, 0.f, 0.f, 0.f, 0.f, 0.f};
    if (row < NN) {
        const float* s = x + (size_t)row * KV + kb;
        if (kb + 8 <= KV) {
            float4 v0 = *(const float4*)s;
            float4 v1 = *(const float4*)(s + 4);
            f[0] = v0.x; f[1] = v0.y; f[2] = v0.z; f[3] = v0.w;
            f[4] = v1.x; f[5] = v1.y; f[6] = v1.z; f[7] = v1.w;
        } else {
#pragma unroll
            for (int j = 0; j < 8; ++j)
                if (kb + j < KV) f[j] = s[j];
        }
    }
    ushort v[8];
#pragma unroll
    for (int j = 0; j < 8; ++j) v[j] = f2b(f[j]);
    uint4 pk;
    pk.x = (uint)v[0] | ((uint)v[1] << 16);
    pk.y = (uint)v[2] | ((uint)v[3] << 16);
    pk.z = (uint)v[4] | ((uint)v[5] << 16);
    pk.w = (uint)v[6] | ((uint)v[7] << 16);
    *(uint4*)(xb + (size_t)row * KP1 + kb) = pk;
}

// all weight conversions in one launch; 8-element groups, segmented if-chain
__global__ __launch_bounds__(256) void k_cvt_wall(const float* __restrict__ w1l,
                                                  const float* __restrict__ w1r,
                                                  const float* __restrict__ w2l,
                                                  const float* __restrict__ w2r,
                                                  const float* __restrict__ cw1,
                                                  ushort* __restrict__ wcat1,
                                                  ushort* __restrict__ wcat2,
                                                  ushort* __restrict__ cw1b) {
    int i = blockIdx.x * 256 + threadIdx.x;
    // group counts: seg0/1: 256*40, seg2/3: 256*32, seg4: 128*32
    const float* src; ushort* dst; int row, kb, Kin;
    if (i < 10240)            { int g = i;          row = g / 40; kb = (g % 40) * 8; src = w1l; dst = wcat1;                       Kin = KV; }
    else if (i < 20480)       { int g = i - 10240;  row = g / 40; kb = (g % 40) * 8; src = w1r; dst = wcat1 + (size_t)256 * KP1;   Kin = KV; }
    else if (i < 28672)       { int g = i - 20480;  row = g / 32; kb = (g % 32) * 8; src = w2l; dst = wcat2;                       Kin = DE; }
    else if (i < 36864)       { int g = i - 28672;  row = g / 32; kb = (g % 32) * 8; src = w2r; dst = wcat2 + (size_t)256 * DE;    Kin = DE; }
    else if (i < 40960)       { int g = i - 36864;  row = g / 32; kb = (g % 32) * 8; src = cw1; dst = cw1b;                        Kin = DE; }
    else return;
    int KPr = (Kin == KV) ? KP1 : DE;
    const float* s = src + (size_t)row * Kin + kb;
    float f[8] = {0.f, 0.f, 0.f, 0.f, 0.f, 0.f, 0.f, 0.f};
    if (kb + 8 <= Kin) {
        float4 v0 = *(const float4*)s;
        float4 v1 = *(const float4*)(s + 4);
        f[0] = v0.x; f[1] = v0.y; f[2] = v0.z; f[3] = v0.w;
        f[4] = v1.x; f[5] = v1.y; f[6] = v1.z; f[7] = v1.w;
    } else {
#pragma unroll
        for (int j = 0; j < 8; ++j)
            if (kb + j < Kin) f[j] = s[j];
    }
    ushort v[8];
#pragma unroll
    for (int j = 0; j < 8; ++j) v[j] = f2b(f[j]);
    uint4 pk;
    pk.x = (uint)v[0] | ((uint)v[1] << 16);
    pk.y = (uint)v[2] | ((uint)v[3] << 16);
    pk.z = (uint)v[4] | ((uint)v[5] << 16);
    pk.w = (uint)v[6] | ((uint)v[7] << 16);
    *(uint4*)(dst + (size_t)row * KPr + kb) = pk;
}

// -------------------------------------------------------------- layer GEMM
// [y_l | y_r] = A[M,KPr] @ Wcat[512,KPr]^T ; y_l (cols 0..255) -> fp8 ybuf,
// y_r (cols 256..511) -> bf16 yrb. 128x128 tile, 4 waves, BK=64, XOR swizzle.
__global__ __launch_bounds__(256) void k_mgemm_layer(const ushort* __restrict__ A,
                                                     const ushort* __restrict__ B,
                                                     unsigned char* __restrict__ ybuf,
                                                     ushort* __restrict__ yrb,
                                                     int KPr) {
    __shared__ __align__(16) ushort As[128 * 64];
    __shared__ __align__(16) ushort Bs[128 * 64];
    const int t = threadIdx.x;
    const int bn = blockIdx.x * 128;
    const int bm = blockIdx.y * 128;
    const int w = t >> 6;
    const int lane = t & 63;
    const int wr = (w >> 1) * 64, wc = (w & 1) * 64;
    const int fr = lane & 15;
    const int fg = lane >> 4;
    const int drow = (lane >> 4) * 4;
    const int dcol = lane & 15;

    f32x4 acc[4][4];
#pragma unroll
    for (int m = 0; m < 4; ++m)
#pragma unroll
        for (int n = 0; n < 4; ++n) acc[m][n] = (f32x4){0.f, 0.f, 0.f, 0.f};

    const int srow = lane >> 3;
    const int sblk = (lane & 7) ^ srow;
    const ushort* Ab = A + (size_t)(bm + w * 32 + srow) * KPr + sblk * 8;
    const ushort* Bb = B + (size_t)(bn + w * 32 + srow) * KPr + sblk * 8;
    ushort* Al = As + w * 2048 + lane * 8;
    ushort* Bl = Bs + w * 2048 + lane * 8;

    for (int k0 = 0; k0 < KPr; k0 += 64) {
#pragma unroll
        for (int j = 0; j < 4; ++j) {
            gload_lds16(Ab + k0 + (size_t)j * 8 * KPr, Al + j * 512);
            gload_lds16(Bb + k0 + (size_t)j * 8 * KPr, Bl + j * 512);
        }
        __syncthreads();
#pragma unroll
        for (int ks = 0; ks < 2; ++ks) {
            bf16x8 af[4], bfr[4];
#pragma unroll
            for (int m = 0; m < 4; ++m) {
                int row = wr + 16 * m + fr;
                int blk = (fg + 4 * ks) ^ (row & 7);
                af[m] = *(const bf16x8*)(As + row * 64 + blk * 8);
            }
#pragma unroll
            for (int n = 0; n < 4; ++n) {
                int row = wc + 16 * n + fr;
                int blk = (fg + 4 * ks) ^ (row & 7);
                bfr[n] = *(const bf16x8*)(Bs + row * 64 + blk * 8);
            }
#pragma unroll
            for (int m = 0; m < 4; ++m)
#pragma unroll
                for (int n = 0; n < 4; ++n)
                    acc[m][n] = __builtin_amdgcn_mfma_f32_16x16x32_bf16(
                        af[m], bfr[n], acc[m][n], 0, 0, 0);
        }
        __syncthreads();
    }
#pragma unroll
    for (int m = 0; m < 4; ++m) {
        int gr0 = bm + wr + 16 * m + drow;
#pragma unroll
        for (int n = 0; n < 4; ++n) {
            int gc = bn + wc + 16 * n + dcol;  // block-uniform side of 256
#pragma unroll
            for (int r = 0; r < 4; ++r) {
                float v = acc[m][n][r];
                if (gc < 256) {
                    uint p = __builtin_amdgcn_cvt_pk_fp8_f32(v, v, 0, false);
                    ybuf[(size_t)(gr0 + r) * 256 + gc] = (unsigned char)(p & 0xff);
                } else {
                    yrb[(size_t)(gr0 + r) * 256 + (gc - 256)] = f2b(v);
                }
            }
        }
    }
}

// ----------------------------------------------- classifier GEMM + logits
// hid = relu(h2b @ cw1b^T + cb1) kept in LDS; logits = hid @ cw2^T + cb2.
__global__ __launch_bounds__(256) void k_mcls(const ushort* __restrict__ A,
                                              const ushort* __restrict__ B,
                                              const float* __restrict__ cb1,
                                              const float* __restrict__ cw2,
                                              const float* __restrict__ cb2,
                                              float* __restrict__ outp) {
    __shared__ __align__(16) ushort smem[128 * 130];  // As|Bs then hid tile
    __shared__ float cw2s[NC * DF];
    ushort* As = smem;
    ushort* Bs = smem + 8192;
    const int t = threadIdx.x;
    const int bm = blockIdx.y * 128;
    const int w = t >> 6;
    const int lane = t & 63;
    const int wr = (w >> 1) * 64, wc = (w & 1) * 64;
    const int fr = lane & 15;
    const int fg = lane >> 4;
    const int drow = (lane >> 4) * 4;
    const int dcol = lane & 15;

    for (int i = t; i < NC * DF; i += 256) cw2s[i] = cw2[i];

    f32x4 acc[4][4];
#pragma unroll
    for (int m = 0; m < 4; ++m)
#pragma unroll
        for (int n = 0; n < 4; ++n) acc[m][n] = (f32x4){0.f, 0.f, 0.f, 0.f};

    const int srow = lane >> 3;
    const int sblk = (lane & 7) ^ srow;
    const ushort* Ab = A + (size_t)(bm + w * 32 + srow) * DE + sblk * 8;
    const ushort* Bb = B + (size_t)(w * 32 + srow) * DE + sblk * 8;
    ushort* Al = As + w * 2048 + lane * 8;
    ushort* Bl = Bs + w * 2048 + lane * 8;

    for (int k0 = 0; k0 < DE; k0 += 64) {
#pragma unroll
        for (int j = 0; j < 4; ++j) {
            gload_lds16(Ab + k0 + (size_t)j * 8 * DE, Al + j * 512);
            gload_lds16(Bb + k0 + (size_t)j * 8 * DE, Bl + j * 512);
        }
        __syncthreads();
#pragma unroll
        for (int ks = 0; ks < 2; ++ks) {
            bf16x8 af[4], bfr[4];
#pragma unroll
            for (int m = 0; m < 4; ++m) {
                int row = wr + 16 * m + fr;
                int blk = (fg + 4 * ks) ^ (row & 7);
                af[m] = *(const bf16x8*)(As + row * 64 + blk * 8);
            }
#pragma unroll
            for (int n = 0; n < 4; ++n) {
                int row = wc + 16 * n + fr;
                int blk = (fg + 4 * ks) ^ (row & 7);
                bfr[n] = *(const bf16x8*)(Bs + row * 64 + blk * 8);
            }
#pragma unroll
            for (int m = 0; m < 4; ++m)
#pragma unroll
                for (int n = 0; n < 4; ++n)
                    acc[m][n] = __builtin_amdgcn_mfma_f32_16x16x32_bf16(
                        af[m], bfr[n], acc[m][n], 0, 0, 0);
        }
        __syncthreads();
    }
    // hid tile -> LDS (bf16, row stride 130 => conflict-free logits reads)
#pragma unroll
    for (int m = 0; m < 4; ++m) {
        int lr0 = wr + 16 * m + drow;
#pragma unroll
        for (int n = 0; n < 4; ++n) {
            int f = wc + 16 * n + dcol;
            float bv = cb1[f];
#pragma unroll
            for (int r = 0; r < 4; ++r) {
                float v = fmaxf(acc[m][n][r] + bv, 0.f);
                smem[(lr0 + r) * 130 + f] = f2b(v);
            }
        }
    }
    __syncthreads();
    // logits: 2 threads per node, each covers 64 f
    int node = t >> 1;
    int half = t & 1;
    float p0 = 0.f, p1 = 0.f, p2 = 0.f, p3 = 0.f;
#pragma unroll
    for (int i = 0; i < 32; ++i) {
        uint hv = *(const uint*)&smem[node * 130 + half * 64 + 2 * i];
        float h0 = b2f((ushort)(hv & 0xffff));
        float h1 = b2f((ushort)(hv >> 16));
        int f = half * 64 + 2 * i;
        p0 += h0 * cw2s[0 * DF + f] + h1 * cw2s[0 * DF + f + 1];
        p1 += h0 * cw2s[1 * DF + f] + h1 * cw2s[1 * DF + f + 1];
        p2 += h0 * cw2s[2 * DF + f] + h1 * cw2s[2 * DF + f + 1];
        p3 += h0 * cw2s[3 * DF + f] + h1 * cw2s[3 * DF + f + 1];
    }
    p0 += __shfl_xor(p0, 1, 64);
    p1 += __shfl_xor(p1, 1, 64);
    p2 += __shfl_xor(p2, 1, 64);
    p3 += __shfl_xor(p3, 1, 64);
    int ng = bm + node;
    if (half == 0 && ng < NN) {
        float4 o = make_float4(p0 + cb2[0], p1 + cb2[1], p2 + cb2[2], p3 + cb2[3]);
        *(float4*)(outp + (size_t)ng * NC) = o;
    }
}

// --------------------------------------------------- aggregate + norm (+relu)
// yl: fp8 e4m3 [MP][256] (uint-viewed), yrb: bf16 [MP][256]. One wave/node,
// 8-edge unroll.
__global__ __launch_bounds__(256) void k_aggnorm(const uint* __restrict__ yl,
                                                 const ushort* __restrict__ yrb,
                                                 const float* __restrict__ bias,
                                                 const int* __restrict__ rowptr,
                                                 const int* __restrict__ col,
                                                 float* __restrict__ outf,
                                                 ushort* __restrict__ outb,
                                                 int relu) {
    int wave = threadIdx.x >> 6;
    int lane = threadIdx.x & 63;
    int n = blockIdx.x * 4 + wave;
    if (n >= NN) return;
    int beg = rowptr[n], end = rowptr[n + 1];
    const uint* base = yl + lane;
    float a0 = 0.f, a1 = 0.f, a2 = 0.f, a3 = 0.f;
    float c0 = 0.f, c1 = 0.f, c2 = 0.f, c3 = 0.f;
    int e = beg;
    for (; e + 8 <= end; e += 8) {
        uint v[8];
#pragma unroll
        for (int j = 0; j < 8; ++j) v[j] = base[(size_t)col[e + j] * 64];
#pragma unroll
        for (int j = 0; j < 8; j += 2) {
            a0 += __builtin_amdgcn_cvt_f32_fp8(v[j], 0);
            a1 += __builtin_amdgcn_cvt_f32_fp8(v[j], 1);
            a2 += __builtin_amdgcn_cvt_f32_fp8(v[j], 2);
            a3 += __builtin_amdgcn_cvt_f32_fp8(v[j], 3);
            c0 += __builtin_amdgcn_cvt_f32_fp8(v[j + 1], 0);
            c1 += __builtin_amdgcn_cvt_f32_fp8(v[j + 1], 1);
            c2 += __builtin_amdgcn_cvt_f32_fp8(v[j + 1], 2);
            c3 += __builtin_amdgcn_cvt_f32_fp8(v[j + 1], 3);
        }
    }
    for (; e < end; ++e) {
        uint v = base[(size_t)col[e] * 64];
        a0 += __builtin_amdgcn_cvt_f32_fp8(v, 0);
        a1 += __builtin_amdgcn_cvt_f32_fp8(v, 1);
        a2 += __builtin_amdgcn_cvt_f32_fp8(v, 2);
        a3 += __builtin_amdgcn_cvt_f32_fp8(v, 3);
    }
    a0 += c0; a1 += c1; a2 += c2; a3 += c3;
    int d = end - beg;
    float inv = 1.0f / (float)(d > 1 ? d : 1);
    ushort4 rv = *(const ushort4*)(yrb + (size_t)n * 256 + lane * 4);
    float4 b = *(const float4*)(bias + lane * 4);
    float hx = a0 * inv + b.x + b2f(rv.x);
    float hy = a1 * inv + b.y + b2f(rv.y);
    float hz = a2 * inv + b.z + b2f(rv.z);
    float hw = a3 * inv + b.w + b2f(rv.w);
    float ss = hx * hx + hy * hy + hz * hz + hw * hw;
#pragma unroll
    for (int off = 32; off > 0; off >>= 1) ss += __shfl_xor(ss, off, 64);
    float scale = 1.0f / fmaxf(sqrtf(ss), 1e-12f);
    hx *= scale; hy *= scale; hz *= scale; hw *= scale;
    if (relu) {
        hx = fmaxf(hx, 0.f); hy = fmaxf(hy, 0.f);
        hz = fmaxf(hz, 0.f); hw = fmaxf(hw, 0.f);
    }
    if (outf) {
        float4 o = make_float4(hx, hy, hz, hw);
        *(float4*)(outf + (size_t)n * DE + lane * 4) = o;
    }
    ushort4 ob;
    ob.x = f2b(hx); ob.y = f2b(hy); ob.z = f2b(hz); ob.w = f2b(hw);
    *(ushort4*)(outb + (size_t)n * DE + lane * 4) = ob;
}

// ------------------------------------------------------------------ mask copy
__global__ __launch_bounds__(256) void k_mask(const unsigned char* __restrict__ m8,
                                              float* __restrict__ o) {
    int i = blockIdx.x * 256 + threadIdx.x;
    if (i >= NN) return;
    bool bytes = (m8[1] != 0);
    float v;
    if (bytes) v = (m8[i] != 0) ? 1.0f : 0.0f;
    else       v = (((const int*)m8)[i] != 0) ? 1.0f : 0.0f;
    o[i] = v;
}

// ------------------------------------------------------------------- launcher
extern "C" void kernel_launch(void* const* d_in, const int* in_sizes, int n_in,
                              void* d_out, int out_size, void* d_ws, size_t ws_size,
                              hipStream_t stream) {
    const float* x   = (const float*)d_in[0];
    const int*   ei  = (const int*)d_in[1];
    const void*  msk = d_in[2];
    const float* w1l = (const float*)d_in[3];
    const float* b1l = (const float*)d_in[4];
    const float* w1r = (const float*)d_in[5];
    const float* w2l = (const float*)d_in[6];
    const float* b2l = (const float*)d_in[7];
    const float* w2r = (const float*)d_in[8];
    const float* cw1 = (const float*)d_in[9];
    const float* cb1 = (const float*)d_in[10];
    const float* cw2 = (const float*)d_in[11];
    const float* cb2 = (const float*)d_in[12];

    float* out        = (float*)d_out;
    float* out_logits = out;                              // [N,4]
    float* out_mask   = out + (size_t)NN * NC;            // [N,1]
    float* h2f        = out + (size_t)NN * NC + NN;       // [N,256]

    char* wp = (char*)d_ws;
    auto alloc = [&](size_t bytes) -> void* {
        void* p = (void*)wp;
        wp += (bytes + 255) & ~(size_t)255;
        return p;
    };
    int* counters = (int*)alloc((size_t)2 * NN * 4);
    int* deg  = counters;
    int* cnt2 = counters + NN;
    int* rowptr  = (int*)alloc((size_t)(NN + 1) * 4);
    int* partial = (int*)alloc(256 * 4);
    int* poff    = (int*)alloc(256 * 4);
    int* col     = (int*)alloc((size_t)NE * 4);
    ushort* xb    = (ushort*)alloc((size_t)MP * KP1 * 2);
    ushort* wcat1 = (ushort*)alloc((size_t)512 * KP1 * 2);
    ushort* wcat2 = (ushort*)alloc((size_t)512 * DE * 2);
    ushort* cw1b  = (ushort*)alloc((size_t)DF * DE * 2);
    unsigned char* ybuf = (unsigned char*)alloc((size_t)MP * 256);  // fp8 y_l
    ushort* yrb   = (ushort*)alloc((size_t)MP * 256 * 2);           // bf16 y_r
    ushort* h1b   = (ushort*)alloc((size_t)MP * DE * 2);
    ushort* h2b   = (ushort*)alloc((size_t)MP * DE * 2);

    const int* srcp = ei;
    const int* dstp = ei + NE;

    hipMemsetAsync(counters, 0, (size_t)2 * NN * 4, stream);
    k_degree<<<(NE + 255) / 256, 256, 0, stream>>>(dstp, deg);
    int nb = (NN + 255) / 256;  // 196
    k_scan1<<<nb, 256, 0, stream>>>(deg, partial);
    k_scan2<<<1, 256, 0, stream>>>(partial, poff, nb);
    k_scan3<<<nb, 256, 0, stream>>>(deg, poff, rowptr);
    k_scatter<<<(NE + 255) / 256, 256, 0, stream>>>(srcp, dstp, rowptr, cnt2, col);

    k_cvt_x<<<(MP * (KP1 / 8) + 255) / 256, 256, 0, stream>>>(x, xb);
    k_cvt_wall<<<(40960 + 255) / 256, 256, 0, stream>>>(w1l, w1r, w2l, w2r, cw1,
                                                        wcat1, wcat2, cw1b);

    dim3 g1(512 / 128, MP / 128);  // (4, 391)
    k_mgemm_layer<<<g1, 256, 0, stream>>>(xb, wcat1, ybuf, yrb, KP1);
    k_aggnorm<<<NN / 4, 256, 0, stream>>>((const uint*)ybuf, yrb, b1l, rowptr, col,
                                          nullptr, h1b, 1);
    k_mgemm_layer<<<g1, 256, 0, stream>>>(h1b, wcat2, ybuf, yrb, DE);
    k_aggnorm<<<NN / 4, 256, 0, stream>>>((const uint*)ybuf, yrb, b2l, rowptr, col,
                                          h2f, h2b, 0);

    dim3 g2(1, MP / 128);          // (1, 391)
    k_mcls<<<g2, 256, 0, stream>>>(h2b, cw1b, cb1, cw2, cb2, out_logits);
    k_mask<<<(NN + 255) / 256, 256, 0, stream>>>((const unsigned char*)msk, out_mask);
}